// Round 5
// baseline (434.901 us; speedup 1.0000x reference)
//
#include <hip/hip_runtime.h>

// SKLinear: out = (h @ A_cat @ B_cat)/8 + bias
//   A_cat (4096x1024) = [S1_l cols | U2_l cols], B_cat (1024x4096) = [U1_l rows ; S2_l rows]
// Pipeline: pack A_cat^T,B_cat^T (bf16); GEMM1 (fused f32->bf16 A-staging, split-K=2) -> f32 partials;
//           reduce partials -> T bf16; GEMM2 (2-pass persistent) -> f32 out (/8 + bias, NT stores).

using bf16x8 = __attribute__((ext_vector_type(8))) __bf16;
using u16x8  = __attribute__((ext_vector_type(8))) unsigned short;
using f32x4  = __attribute__((ext_vector_type(4))) float;

__device__ __forceinline__ unsigned short f2bf(float f) {
    union { float f; unsigned u; } c; c.f = f;
    unsigned u = c.u;
    return (unsigned short)((u + 0x7FFFu + ((u >> 16) & 1u)) >> 16);  // RNE
}

__device__ __forceinline__ void gload_lds16(const void* g, void* l) {
    __builtin_amdgcn_global_load_lds((const __attribute__((address_space(1))) void*)g,
                                     (__attribute__((address_space(3))) void*)l,
                                     16, 0, 0);
}

// ---------------- transpose-pack: dst[c*dstStride + r] = bf16(src[r*srcStride + c]) ----------------
__global__ void pack_transpose(const float* __restrict__ p0, const float* __restrict__ p1,
                               unsigned short* __restrict__ dst,
                               int srcStride, int dstStride, long perT, long dstTOff) {
    const int t = blockIdx.z;
    const float* src = (t < 4) ? (p0 + (long)t * perT) : (p1 + (long)(t - 4) * perT);
    unsigned short* d = dst + (long)t * dstTOff;
    const int r0 = blockIdx.x * 32, c0 = blockIdx.y * 32;
    __shared__ float tile[32][33];
    const int tx = threadIdx.x & 31, ty = threadIdx.x >> 5;
#pragma unroll
    for (int j = 0; j < 4; ++j) {
        int rr = ty + j * 8;
        tile[rr][tx] = src[(long)(r0 + rr) * srcStride + c0 + tx];
    }
    __syncthreads();
#pragma unroll
    for (int j = 0; j < 4; ++j) {
        int cc = ty + j * 8;
        d[(long)(c0 + cc) * dstStride + r0 + tx] = f2bf(tile[tx][cc]);
    }
}

// ---------------- reduce: T = bf16(P0 + P1) ----------------
__global__ void reduce_cvt(const float4* __restrict__ a, const float4* __restrict__ b,
                           ushort4* __restrict__ o, int n4) {
    int i = blockIdx.x * blockDim.x + threadIdx.x;
    int stride = gridDim.x * blockDim.x;
    for (; i < n4; i += stride) {
        float4 x = a[i], y = b[i];
        ushort4 r;
        r.x = f2bf(x.x + y.x); r.y = f2bf(x.y + y.y);
        r.z = f2bf(x.z + y.z); r.w = f2bf(x.w + y.w);
        o[i] = r;
    }
}

// ---------------- 8-phase 256x256 GEMM ----------------
// OMODE 0: A is f32 (fused cvt reg-staging), split-K via grid, raw f32 partial out, NPASS=1.
// OMODE 1: A is bf16 (gload_lds), NPASS=2 n-tiles per block, f32 out = acc*scale + bias (NT stores).
#define SB()   __builtin_amdgcn_s_barrier()
#define SCB()  __builtin_amdgcn_sched_barrier(0)
#define WVM0() { asm volatile("s_waitcnt vmcnt(0)" ::: "memory"); SCB(); }
#define WVM4() { asm volatile("s_waitcnt vmcnt(4)" ::: "memory"); SCB(); }
#define WVM8() { asm volatile("s_waitcnt vmcnt(8)" ::: "memory"); SCB(); }
#define WLG()  { asm volatile("s_waitcnt lgkmcnt(0)" ::: "memory"); SCB(); }

template <int NPASS, int OMODE>
__global__ __launch_bounds__(512, 2) void gemm8p(const void* __restrict__ Aq,
                                                 const unsigned short* __restrict__ Bt,
                                                 float* __restrict__ Cf,
                                                 const float* __restrict__ bias,
                                                 const int ld, const int N, const float scale) {
    constexpr bool FUSED = (OMODE == 0);
    constexpr int BM = 256, BN = 256;
    constexpr int KT = (NPASS == 2) ? 16 : 32;   // k-tiles per pass
    constexpr int NTT = 32;                      // total tiles (both kernels)
    constexpr int KTSH = (NPASS == 2) ? 4 : 5;
    constexpr int NSTEP = 2048;                  // n stride between passes
    constexpr int M = 8192;
    constexpr int BUFB = 65536;                  // A 32KB + B 32KB per K-tile buffer
    __shared__ __align__(128) char smem[2 * BUFB];

    const int tid = threadIdx.x;
    const int w = tid >> 6, lane = tid & 63;
    const int wm = w >> 2, wn = w & 3;

    const int nwg = gridDim.x;
    const int wg = blockIdx.x;
    const int swz = (wg & 7) * (nwg >> 3) + (wg >> 3);
    int m0, n0, kbase;
    if constexpr (NPASS == 1) {
        kbase = (swz & 1) * KT * 64;
        n0 = ((swz >> 1) & 3) * BN;
        m0 = (swz >> 3) * BM;
        Cf += (size_t)(swz & 1) * M * (size_t)N;
    } else {
        kbase = 0;
        n0 = (swz & 7) * BN;
        m0 = (swz >> 3) * BM;
    }

    // ---- staging lane constants (B always; A only if !FUSED) ----
    const int rl = lane >> 3;
    const int csw = (lane & 7) ^ rl;
    const unsigned short* gB = Bt + (size_t)(n0 + w * 8 + rl) * ld + kbase + csw * 8;
    const unsigned short* gA16 = FUSED ? nullptr
        : (const unsigned short*)Aq + (size_t)(m0 + w * 8 + rl) * ld + kbase + csw * 8;

    // ---- fused-A lane constants ----
    const int R  = w * 16 + (lane >> 2);         // row in 128-row half
    const int cp = lane & 3;                     // 16B-chunk index (and cp+4)
    const float* gAf = FUSED
        ? (const float*)Aq + (size_t)(m0 + R) * ld + kbase + cp * 8 : nullptr;
    const int sA0 = (R >> 3) * 1024 + (R & 7) * 128 + (((cp)     ^ (R & 7)) << 4);
    const int sA1 = (R >> 3) * 1024 + (R & 7) * 128 + (((cp + 4) ^ (R & 7)) << 4);

    // ---- ds_read lane constants ----
    const int aRB = wm * 16384 + (lane & 15) * 128;
    const int bRB = 32768 + (wn >> 1) * 16384 + ((wn & 1) * 64 + (lane & 15)) * 128;
    const int ch0 = (((lane >> 4) + 0) ^ (lane & 7)) << 4;
    const int ch1 = (((lane >> 4) + 4) ^ (lane & 7)) << 4;

    f32x4 acc[8][4] = {};

#define STAGE_B(tt, h) {                                                                        \
        const unsigned short* g_ = gB + ((size_t)((tt) >> KTSH) * NSTEP + (size_t)(h) * 128) * ld \
                                      + ((tt) & (KT - 1)) * 64;                                 \
        char* l_ = smem + ((tt) & 1) * BUFB + 32768 + (h) * 16384 + w * 1024;                   \
        gload_lds16(g_, l_); gload_lds16(g_ + (size_t)64 * ld, l_ + 8192); }

#define STAGE_A16(tt, h) {                                                                      \
        const unsigned short* g_ = gA16 + (size_t)(h) * 128 * ld + ((tt) & (KT - 1)) * 64;      \
        char* l_ = smem + ((tt) & 1) * BUFB + (h) * 16384 + w * 1024;                           \
        gload_lds16(g_, l_); gload_lds16(g_ + (size_t)64 * ld, l_ + 8192); }

#define ALOAD(tt, h) {                                                                          \
        const float* g_ = gAf + (size_t)(h) * 128 * ld + ((tt) & (KT - 1)) * 64;                \
        ar[h][0] = *(const float4*)(g_);      ar[h][1] = *(const float4*)(g_ + 4);              \
        ar[h][2] = *(const float4*)(g_ + 32); ar[h][3] = *(const float4*)(g_ + 36); }

#define AWRITE(tt, h) {                                                                         \
        char* l_ = smem + ((tt) & 1) * BUFB + (h) * 16384;                                      \
        u16x8 p0_, p1_;                                                                         \
        p0_[0] = f2bf(ar[h][0].x); p0_[1] = f2bf(ar[h][0].y);                                   \
        p0_[2] = f2bf(ar[h][0].z); p0_[3] = f2bf(ar[h][0].w);                                   \
        p0_[4] = f2bf(ar[h][1].x); p0_[5] = f2bf(ar[h][1].y);                                   \
        p0_[6] = f2bf(ar[h][1].z); p0_[7] = f2bf(ar[h][1].w);                                   \
        p1_[0] = f2bf(ar[h][2].x); p1_[1] = f2bf(ar[h][2].y);                                   \
        p1_[2] = f2bf(ar[h][2].z); p1_[3] = f2bf(ar[h][2].w);                                   \
        p1_[4] = f2bf(ar[h][3].x); p1_[5] = f2bf(ar[h][3].y);                                   \
        p1_[6] = f2bf(ar[h][3].z); p1_[7] = f2bf(ar[h][3].w);                                   \
        *(u16x8*)(l_ + sA0) = p0_; *(u16x8*)(l_ + sA1) = p1_; }

#define DUMP(p) {                                                                               \
        const int lc_ = lane & 15, lr_ = (lane >> 4) * 4;                                       \
        _Pragma("unroll") for (int fm_ = 0; fm_ < 8; ++fm_) {                                   \
            const int row_ = m0 + wm * 128 + fm_ * 16 + lr_;                                    \
            _Pragma("unroll") for (int q_ = 0; q_ < 4; ++q_) {                                  \
                _Pragma("unroll") for (int fn_ = 0; fn_ < 4; ++fn_) {                           \
                    const int col_ = n0 + (p) * NSTEP + wn * 64 + fn_ * 16 + lc_;               \
                    if constexpr (OMODE == 0) {                                                 \
                        Cf[(size_t)(row_ + q_) * N + col_] = acc[fm_][fn_][q_];                 \
                    } else {                                                                    \
                        __builtin_nontemporal_store(acc[fm_][fn_][q_] * scale + bias[col_],     \
                                                    Cf + (size_t)(row_ + q_) * N + col_);       \
                    } } } } }

#define CLRACC() { _Pragma("unroll") for (int i_ = 0; i_ < 8; ++i_)                             \
        _Pragma("unroll") for (int j_ = 0; j_ < 4; ++j_) acc[i_][j_] = (f32x4){0.f, 0.f, 0.f, 0.f}; }

    if constexpr (FUSED) {
        // =================== GEMM1: fused-cvt A, split-K, 4x av-reread phases ===================
        bf16x8 av4[4][2], bv[4][2];
        float4 ar[2][4];

#define LOADA4(c, mb) { _Pragma("unroll") for (int f_ = 0; f_ < 4; ++f_) {                      \
            const char* p_ = smem + (c) * BUFB + aRB + ((mb) + f_) * 2048;                      \
            av4[f_][0] = *(const bf16x8*)(p_ + ch0); av4[f_][1] = *(const bf16x8*)(p_ + ch1); } }
#define LOADB2F(c, pb) { _Pragma("unroll") for (int f_ = 0; f_ < 2; ++f_) {                     \
            const char* p_ = smem + (c) * BUFB + bRB + ((pb) * 2 + f_) * 2048;                  \
            bv[(pb) * 2 + f_][0] = *(const bf16x8*)(p_ + ch0);                                  \
            bv[(pb) * 2 + f_][1] = *(const bf16x8*)(p_ + ch1); } }
#define BURST4(mb, nb) { __builtin_amdgcn_s_setprio(1);                                         \
            _Pragma("unroll") for (int f_ = 0; f_ < 4; ++f_)                                    \
            _Pragma("unroll") for (int g_ = 0; g_ < 2; ++g_) {                                  \
                acc[(mb) + f_][(nb) + g_] = __builtin_amdgcn_mfma_f32_16x16x32_bf16(            \
                    av4[f_][0], bv[(nb) + g_][0], acc[(mb) + f_][(nb) + g_], 0, 0, 0);          \
                acc[(mb) + f_][(nb) + g_] = __builtin_amdgcn_mfma_f32_16x16x32_bf16(            \
                    av4[f_][1], bv[(nb) + g_][1], acc[(mb) + f_][(nb) + g_], 0, 0, 0); }        \
            __builtin_amdgcn_s_setprio(0); }

        // prologue: A(0) load+write, B(0) stage, A(1) load (stays in regs)
        ALOAD(0, 0); ALOAD(0, 1);
        AWRITE(0, 0); AWRITE(0, 1);
        WLG();                                  // drain own ds_writes before first barrier
        STAGE_B(0, 0); STAGE_B(0, 1);
        ALOAD(1, 0); ALOAD(1, 1);

        for (int tt = 0; tt < NTT - 1; ++tt) {
            const int c = tt & 1;
            WVM8(); SB();
            // P1
            LOADA4(c, 0); LOADB2F(c, 0);
            AWRITE(tt + 1, 0);
            STAGE_B(tt + 1, 0);
            SB(); WLG();
            BURST4(0, 0);
            SB();
            // P2
            LOADA4(c, 4); LOADB2F(c, 1);
            AWRITE(tt + 1, 1);
            STAGE_B(tt + 1, 1);
            SB(); WLG();
            BURST4(4, 2);
            SB();
            // P3
            LOADA4(c, 0);
            if (tt + 2 < NTT) ALOAD(tt + 2, 0);
            SB(); WLG();
            BURST4(0, 2);
            SB();
            // P4
            LOADA4(c, 4);
            if (tt + 2 < NTT) ALOAD(tt + 2, 1);
            SB(); WLG();
            BURST4(4, 0);
        }
        {   // peeled tile 31 (buffer 1; its A was written during tt=30 P1/P2)
            WVM0(); SB();
            LOADA4(1, 0); LOADB2F(1, 0); SB(); WLG(); BURST4(0, 0); SB();
            LOADA4(1, 4); LOADB2F(1, 1); SB(); WLG(); BURST4(4, 2); SB();
            LOADA4(1, 0); SB(); WLG(); BURST4(0, 2); SB();
            LOADA4(1, 4); SB(); WLG(); BURST4(4, 0);
        }
        DUMP(0);
#undef LOADA4
#undef LOADB2F
#undef BURST4
    } else {
        // =================== GEMM2: bf16 A via gload_lds, 2-pass persistent ===================
        bf16x8 av[8][2], bv[4][2];

#define LOADA(c, base) { _Pragma("unroll") for (int f_ = 0; f_ < 4; ++f_) {                     \
            const char* p_ = smem + (c) * BUFB + aRB + ((base) + f_) * 2048;                    \
            av[(base) + f_][0] = *(const bf16x8*)(p_ + ch0);                                    \
            av[(base) + f_][1] = *(const bf16x8*)(p_ + ch1); } }
#define LOADB(c, base) { _Pragma("unroll") for (int f_ = 0; f_ < 2; ++f_) {                     \
            const char* p_ = smem + (c) * BUFB + bRB + ((base) + f_) * 2048;                    \
            bv[(base) + f_][0] = *(const bf16x8*)(p_ + ch0);                                    \
            bv[(base) + f_][1] = *(const bf16x8*)(p_ + ch1); } }
#define BURST(mb, nb) { __builtin_amdgcn_s_setprio(1);                                          \
            _Pragma("unroll") for (int f_ = 0; f_ < 4; ++f_)                                    \
            _Pragma("unroll") for (int g_ = 0; g_ < 2; ++g_) {                                  \
                acc[(mb) + f_][(nb) + g_] = __builtin_amdgcn_mfma_f32_16x16x32_bf16(            \
                    av[(mb) + f_][0], bv[(nb) + g_][0], acc[(mb) + f_][(nb) + g_], 0, 0, 0);    \
                acc[(mb) + f_][(nb) + g_] = __builtin_amdgcn_mfma_f32_16x16x32_bf16(            \
                    av[(mb) + f_][1], bv[(nb) + g_][1], acc[(mb) + f_][(nb) + g_], 0, 0, 0); }  \
            __builtin_amdgcn_s_setprio(0); }

        STAGE_A16(0, 0); STAGE_A16(0, 1);
        STAGE_B(0, 0); STAGE_B(0, 1);
        STAGE_A16(1, 0); STAGE_A16(1, 1);

        for (int tt = 0; tt < NTT - 1; ++tt) {
            const int c = tt & 1;
            if (NPASS == 2 && tt == KT) { WVM0(); } else { WVM4(); }
            SB();
            // P1
            LOADA(c, 0); LOADB(c, 0);
            STAGE_B(tt + 1, 0);
            SB(); WLG();
            BURST(0, 0);
            SB();
            // P2
            LOADA(c, 4); LOADB(c, 2);
            STAGE_B(tt + 1, 1);
            SB(); WLG();
            BURST(4, 0);
            SB();
            // P3
            if (tt + 2 < NTT) STAGE_A16(tt + 2, 0);
            SB();
            BURST(0, 2);
            SB();
            // P4
            if (tt + 2 < NTT) STAGE_A16(tt + 2, 1);
            SB();
            BURST(4, 2);
            if (NPASS == 2 && tt == KT - 1) { DUMP(0); CLRACC(); }
        }
        {   // peeled tile 31
            WVM0(); SB();
            LOADA(1, 0); LOADB(1, 0); SB(); WLG(); BURST(0, 0); SB();
            LOADA(1, 4); LOADB(1, 2); SB(); WLG(); BURST(4, 0); SB();
            BURST(0, 2); SB(); BURST(4, 2);
        }
        DUMP(NPASS - 1);
#undef LOADA
#undef LOADB
#undef BURST
    }
#undef STAGE_B
#undef STAGE_A16
#undef ALOAD
#undef AWRITE
#undef DUMP
#undef CLRACC
}

extern "C" void kernel_launch(void* const* d_in, const int* in_sizes, int n_in,
                              void* d_out, int out_size, void* d_ws, size_t ws_size,
                              hipStream_t stream) {
    const float* h_in = (const float*)d_in[0];  // (8192, 4096)
    const float* S1s  = (const float*)d_in[1];  // (4, 4096, 128)
    const float* S2s  = (const float*)d_in[2];  // (4, 128, 4096)
    const float* U1s  = (const float*)d_in[3];  // (4, 128, 4096)
    const float* U2s  = (const float*)d_in[4];  // (4, 4096, 128)
    const float* bias = (const float*)d_in[5];  // (4096,)
    float* out = (float*)d_out;                 // (8192, 4096) f32

    constexpr int B = 8192, IN = 4096, OUTD = 4096, R = 128;
    constexpr int NC = 1024;  // 2*L*R

    char* ws = (char*)d_ws;                                             // 96 MiB total
    unsigned short* AcatT = (unsigned short*)ws;                        //  8 MiB: A_cat^T (NC x IN)
    unsigned short* BcatT = (unsigned short*)(ws + ((size_t)8 << 20));  //  8 MiB: B_cat^T (OUT x NC)
    unsigned short* T     = (unsigned short*)(ws + ((size_t)16 << 20)); // 16 MiB: T bf16 (B x NC)
    float*          Tp    = (float*)(ws + ((size_t)32 << 20));          // 64 MiB: 2x f32 partials

    // A_cat^T[n = t*128+r][i] = (t<4 ? S1s[t][i][r] : U2s[t-4][i][r])
    pack_transpose<<<dim3(IN / 32, R / 32, 8), 256, 0, stream>>>(
        S1s, U2s, AcatT, R, IN, (long)IN * R, (long)R * IN);
    // B_cat^T[o][n = t*128+r] = (t<4 ? U1s[t][r][o] : S2s[t-4][r][o])
    pack_transpose<<<dim3(R / 32, OUTD / 32, 8), 256, 0, stream>>>(
        U1s, S2s, BcatT, OUTD, NC, (long)R * OUTD, (long)R);

    // GEMM1: Tp[ks] = h(f32, fused cvt) @ AcatT^T over K-slice ks*2048..+2048; 256 blocks
    gemm8p<1, 0><<<dim3(256), 512, 0, stream>>>(
        (const void*)h_in, AcatT, Tp, nullptr, IN, NC, 1.0f);

    // reduce: T = bf16(Tp0 + Tp1)
    reduce_cvt<<<2048, 256, 0, stream>>>(
        (const float4*)Tp, (const float4*)(Tp + (size_t)B * NC), (ushort4*)T, B * NC / 4);

    // GEMM2: out = T @ BcatT^T * (1/8) + bias; 256 blocks, 2 n-passes each
    gemm8p<2, 1><<<dim3(256), 512, 0, stream>>>(
        (const void*)T, BcatT, out, bias, NC, OUTD, 0.125f);
}